// Round 12
// baseline (1943.539 us; speedup 1.0000x reference)
//
#include <hip/hip_runtime.h>

#define NN 50000
#define DD 32
#define BLK 256
#define BSH 7  // bucket = src >> BSH
#define NB 512 // allocated bucket slots (391 used)

typedef float f32x4 __attribute__((ext_vector_type(4)));
typedef _Float16 f16x8 __attribute__((ext_vector_type(8)));
typedef __fp16 fp16x2 __attribute__((ext_vector_type(2)));

struct __align__(8) EdgeRec {
    float a;
    int e;  // original edge id
};

union H8 {
    f16x8 h;
    unsigned u[4];
    uint4 u4;
};

__device__ __forceinline__ float lrelu(float x) { return fmaxf(x, 0.01f * x); }

__device__ __forceinline__ f32x4 lrelu4(f32x4 v) {
    f32x4 r;
    r[0] = fmaxf(v[0], 0.01f * v[0]);
    r[1] = fmaxf(v[1], 0.01f * v[1]);
    r[2] = fmaxf(v[2], 0.01f * v[2]);
    r[3] = fmaxf(v[3], 0.01f * v[3]);
    return r;
}

__device__ __forceinline__ unsigned pkrtz(float a, float b) {
    union {
        fp16x2 h;
        unsigned u;
    } x;
    x.h = __builtin_amdgcn_cvt_pkrtz(a, b);
    return x.u;
}

__device__ __forceinline__ f32x4 ld4(const float* __restrict__ p) {
    return *(const f32x4*)p;
}

__device__ __forceinline__ void lds_copy(float* dst, const float* __restrict__ src, int n) {
    for (int i = threadIdx.x; i < n; i += blockDim.x) dst[i] = src[i];
}

// ---------------- CSR build ----------------
// one pass: node histogram + bucket histogram
__global__ __launch_bounds__(256) void k_hist2(const int* __restrict__ ei, int* __restrict__ cnt,
                                               int* __restrict__ bh, int nE) {
    int e = blockIdx.x * 256 + threadIdx.x;
    if (e >= nE) return;
    int src = ei[e];
    atomicAdd(&cnt[src], 1);
    atomicAdd(&bh[src >> BSH], 1);
}

__global__ __launch_bounds__(1024) void k_scan(int* __restrict__ cnt_cur, int* __restrict__ off,
                                               int nN) {
    __shared__ int part[1024];
    int t = threadIdx.x;
    const int CH = (nN + 1023) / 1024;
    int beg = t * CH, end = min(beg + CH, nN);
    int sum = 0;
    for (int i = beg; i < end; ++i) sum += cnt_cur[i];
    part[t] = sum;
    __syncthreads();
    for (int ofs = 1; ofs < 1024; ofs <<= 1) {
        int v = (t >= ofs) ? part[t - ofs] : 0;
        __syncthreads();
        part[t] += v;
        __syncthreads();
    }
    int run = (t == 0) ? 0 : part[t - 1];
    for (int i = beg; i < end; ++i) {
        int c = cnt_cur[i];
        off[i] = run;
        cnt_cur[i] = run;  // cursor copy
        run += c;
    }
    if (t == 1023) off[nN] = part[1023];
}

// pass A: append {a,e,src} into coarse-bucket staging (sequential per bucket front)
__global__ __launch_bounds__(256) void k_fillA(const int* __restrict__ ei,
                                               const float* __restrict__ ea,
                                               int* __restrict__ bcur, float* __restrict__ sa,
                                               int* __restrict__ se, int* __restrict__ ss,
                                               int nE) {
    int e = blockIdx.x * 256 + threadIdx.x;
    if (e >= nE) return;
    int src = ei[e];
    int pos = atomicAdd(&bcur[src >> BSH], 1);
    sa[pos] = ea[e];
    se[pos] = e;
    ss[pos] = src;
}

// pass B: staging (bucket-grouped) -> exact slots; writes land in ~40KB L2 regions
__global__ __launch_bounds__(256) void k_fillB(const float* __restrict__ sa,
                                               const int* __restrict__ se,
                                               const int* __restrict__ ss, int* __restrict__ cur,
                                               EdgeRec* __restrict__ rec, int nE) {
    int p = blockIdx.x * 256 + threadIdx.x;
    if (p >= nE) return;
    int src = ss[p];
    int slot = atomicAdd(&cur[src], 1);
    reinterpret_cast<int2*>(rec)[slot] = make_int2(__float_as_int(sa[p]), se[p]);
}

// nstart[b] = node containing slot min(b*BLK, nE-1)
__global__ __launch_bounds__(256) void k_bstart(const int* __restrict__ offs,
                                                int* __restrict__ nstart, int nB, int nE) {
    int b = blockIdx.x * 256 + threadIdx.x;
    if (b > nB) return;
    int s = min(b * BLK, nE - 1);
    int lo = 0, hi = NN - 1;
    while (lo < hi) {
        int mid = (lo + hi + 1) >> 1;
        if (offs[mid] <= s) lo = mid;
        else hi = mid - 1;
    }
    nstart[b] = lo;
}

// ---- prep: affine-in-a folds. pre = [c1,d1,cu,du,ch,dh] (6x32) ----
__global__ __launch_bounds__(192) void k_prep(const float* __restrict__ w_in,
                                              const float* __restrict__ b_in,
                                              const float* __restrict__ tw1,
                                              const float* __restrict__ tb1,
                                              const float* __restrict__ uw1,
                                              const float* __restrict__ ub1,
                                              const float* __restrict__ hw1,
                                              const float* __restrict__ hb1,
                                              float* __restrict__ pre) {
    int t = threadIdx.x;
    int which = t >> 5, f = t & 31;
    if (which >= 6) return;
    const float* W = (which < 2) ? tw1 : (which < 4) ? uw1 : hw1;
    const float* x = (which & 1) ? b_in : w_in;
    const float* badd = (which == 1) ? tb1 : (which == 3) ? ub1 : (which == 5) ? hb1 : nullptr;
    float s = badd ? badd[f] : 0.f;
    for (int k = 0; k < 32; ++k) s = fmaf(x[k], W[k * 32 + f], s);
    pre[which * 32 + f] = s;
}

// ---- prep2: fold adjacent linear maps + pack f16 MFMA A-fragments ----
// fold: [0)WA [1024)WB [2048)WC [3072)WD [4096)WE [5120)vB [5152)vC [5184)vD
//       [5216)addg2 [5248)dh2
// fragu: A-frags for {0=WB,1=WA,2=WE,3=hw2}, 2 tiles each; phi = S-perm for m<3.
__global__ __launch_bounds__(256) void k_prep2(
    const float* __restrict__ tw1, const float* __restrict__ tb1, const float* __restrict__ tw2,
    const float* __restrict__ tb2, const float* __restrict__ uw1, const float* __restrict__ ub1,
    const float* __restrict__ uw2, const float* __restrict__ ub2, const float* __restrict__ hw1,
    const float* __restrict__ hw2, const float* __restrict__ pre, float* __restrict__ fold,
    unsigned* __restrict__ fragu) {
    for (int e = threadIdx.x; e < 5 * 1024 + 5 * 32; e += 256) {
        if (e < 5120) {
            int m = e >> 10, r = e & 1023, i = r >> 5, j = r & 31;
            const float* A;
            const float* B;
            switch (m) {
                case 0: A = uw2;        B = uw1 + 2048; break;
                case 1: A = uw2;        B = tw1 + 1024; break;
                case 2: A = tw2;        B = uw1 + 1024; break;
                case 3: A = tw2 + 1024; B = uw1 + 3072; break;
                default: A = uw2 + 1024; B = hw1 + 1024; break;
            }
            float s = 0.f;
            for (int k = 0; k < 32; ++k) s = fmaf(A[i * 32 + k], B[k * 32 + j], s);
            fold[e] = s;
        } else {
            int r = e - 5120;
            int v = r >> 5, f = r & 31;
            const float* x;
            const float* B;
            float s;
            switch (v) {
                case 0: x = ub2;      B = tw1 + 1024; s = tb1[32 + f]; break;  // vB
                case 1: x = tb2;      B = uw1 + 1024; s = 0.f;         break;  // vC
                case 2: x = tb2 + 32; B = uw1 + 3072; s = 0.f;         break;  // vD
                case 3: x = ub2;      B = uw1 + 2048; s = ub1[32 + f]; break;  // addg2
                default: x = ub2 + 32; B = hw1 + 1024; s = pre[160 + f]; break;  // dh2
            }
            for (int k = 0; k < 32; ++k) s = fmaf(x[k], B[k * 32 + f], s);
            fold[e] = s;
        }
    }
    __syncthreads();
    for (int idx = threadIdx.x; idx < 2048; idx += 256) {
        int d = idx & 3;
        int l = (idx >> 2) & 63;
        int T = (idx >> 8) & 1;
        int m = idx >> 9;
        int row = 16 * T + (l & 15);
        int k0 = ((l >> 4) << 3) + 2 * d;
        const float* W = (m == 0) ? fold + 1024 : (m == 1) ? fold : (m == 2) ? fold + 4096 : hw2;
        int phi = (m == 3) ? row : (((row >> 2) & 3) * 8 + ((row >> 4) << 2) + (row & 3));
        union {
            _Float16 h[2];
            unsigned u;
        } P;
        P.h[0] = (_Float16)W[k0 * 32 + phi];
        P.h[1] = (_Float16)W[(k0 + 1) * 32 + phi];
        fragu[idx] = P.u;
    }
}

// ---- fused accum0: per-edge v=lrelu(a*c1+d1), block-local segment-sum -> M0 ----
__global__ __launch_bounds__(256) void k_accum0f(const EdgeRec* __restrict__ rec,
                                                 const int* __restrict__ offs,
                                                 const int* __restrict__ nstart,
                                                 const float* __restrict__ pre,
                                                 float* __restrict__ M0, int nE) {
    __shared__ float zs[256 * 33];
    __shared__ int woff[260];
    __shared__ int sh2[2];
    int tid = threadIdx.x, b = blockIdx.x;
    int s0 = b * BLK, s1 = min(s0 + BLK, nE);
    if (tid == 0) {
        int nlo = nstart[b];
        sh2[0] = nlo;
        sh2[1] = nstart[b + 1] - nlo + 1;
    }
    __syncthreads();
    int nlo = sh2[0], nwin = sh2[1];
    for (int i = tid; i < nwin + 1; i += 256) woff[i] = offs[nlo + i];
    int s = s0 + tid;
    if (s < s1) {
        float a = rec[s].a;
#pragma unroll
        for (int f = 0; f < DD; ++f) zs[tid * 33 + f] = lrelu(fmaf(a, pre[f], pre[32 + f]));
    }
    __syncthreads();
    for (int t = tid; t < nwin * DD; t += 256) {
        int ln = t >> 5, f = t & 31;
        int lo = max(woff[ln], s0), hi = min(woff[ln + 1], s1);
        if (lo >= hi) continue;
        float sum = 0.f;
        for (int j = lo; j < hi; ++j) sum += zs[(j - s0) * 33 + f];
        int n = nlo + ln;
        bool interior = (woff[ln] >= s0) && (woff[ln + 1] <= s1);
        if (interior) M0[(size_t)n * DD + f] = sum;
        else atomicAdd(&M0[(size_t)n * DD + f], sum);
    }
}

// ---- gnode: g[n] = addv + deg*dv + M[n]@W ----
__global__ __launch_bounds__(256) void k_gnode(const float* __restrict__ M,
                                               const float* __restrict__ W,
                                               const float* __restrict__ dv,
                                               const float* __restrict__ addv,
                                               const int* __restrict__ off, float* __restrict__ g) {
    __shared__ float LW[1088];
    lds_copy(LW, W, 1024);
    lds_copy(LW + 1024, dv, 32);
    lds_copy(LW + 1056, addv, 32);
    __syncthreads();
    int tid = blockIdx.x * 256 + threadIdx.x;
    int n = tid >> 5, f = tid & 31;
    if (n >= NN) return;
    float deg = (float)(off[n + 1] - off[n]);
    const float* srow = M + (size_t)n * DD;
    float acc = fmaf(deg, LW[1024 + f], LW[1056 + f]);
    for (int k = 0; k < 32; ++k) acc = fmaf(srow[k], LW[k * 32 + f], acc);
    g[(size_t)n * DD + f] = acc;
}

// ---- z1 via MFMA; src derived from woff (snode map) ----
__global__ __launch_bounds__(256) void k_z1m(const EdgeRec* __restrict__ rec,
                                             const int* __restrict__ offs,
                                             const int* __restrict__ nstart,
                                             const float* __restrict__ pre,
                                             const float* __restrict__ fold,
                                             const unsigned* __restrict__ fragu,
                                             const float* __restrict__ g1, float* __restrict__ Z1,
                                             int nE) {
    __shared__ __align__(16) float zs[256 * 36];
    __shared__ int woff[260];
    __shared__ int snode[BLK];
    __shared__ int sh2[2];
    int tid = threadIdx.x, b = blockIdx.x;
    int s0 = b * BLK, s1 = min(s0 + BLK, nE);
    if (tid == 0) {
        int nlo = nstart[b];
        sh2[0] = nlo;
        sh2[1] = nstart[b + 1] - nlo + 1;
    }
    snode[tid] = 0;
    __syncthreads();
    int nlo = sh2[0], nwin = sh2[1];
    for (int i = tid; i < nwin + 1; i += 256) woff[i] = offs[nlo + i];
    __syncthreads();
    for (int t = tid; t < nwin; t += 256) {
        int lo = max(woff[t], s0), hi = min(woff[t + 1], s1);
        for (int j = lo; j < hi; ++j) snode[j - s0] = t;
    }
    __syncthreads();

    int l = tid & 63, g = l >> 4, e = l & 15, wv = tid >> 6;
    const uint4* fb = (const uint4*)fragu;
    H8 WB0, WB1;
    WB0.u4 = fb[0 + l];
    WB1.u4 = fb[64 + l];
    f32x4 cua = ld4(pre + 64 + 8 * g), cub = ld4(pre + 64 + 8 * g + 4);
    f32x4 vBa = ld4(fold + 5120 + 8 * g), vBb = ld4(fold + 5120 + 8 * g + 4);

    for (int c = 0; c < 4; ++c) {
        int ls = wv * 64 + c * 16 + e;
        int slot = s0 + ls;
        int sc = min(slot, nE - 1);
        float a = rec[sc].a;
        int n = nlo + snode[ls];
        const float* g1p = g1 + (size_t)n * DD + 8 * g;
        f32x4 ma = lrelu4(a * cua + ld4(g1p));
        f32x4 mb = lrelu4(a * cub + ld4(g1p + 4));
        H8 B;
        B.u[0] = pkrtz(ma[0], ma[1]);
        B.u[1] = pkrtz(ma[2], ma[3]);
        B.u[2] = pkrtz(mb[0], mb[1]);
        B.u[3] = pkrtz(mb[2], mb[3]);
        f32x4 z0 = __builtin_amdgcn_mfma_f32_16x16x32_f16(WB0.h, B.h, vBa, 0, 0, 0);
        f32x4 z1 = __builtin_amdgcn_mfma_f32_16x16x32_f16(WB1.h, B.h, vBb, 0, 0, 0);
        z0 = lrelu4(z0);
        z1 = lrelu4(z1);
        *(f32x4*)&zs[ls * 36 + 8 * g] = z0;
        *(f32x4*)&zs[ls * 36 + 8 * g + 4] = z1;
    }
    __syncthreads();
    for (int t = tid; t < nwin * DD; t += 256) {
        int ln = t >> 5, f = t & 31;
        int lo = max(woff[ln], s0), hi = min(woff[ln + 1], s1);
        if (lo >= hi) continue;
        float sum = 0.f;
        for (int j = lo; j < hi; ++j) sum += zs[(j - s0) * 36 + f];
        int n = nlo + ln;
        bool interior = (woff[ln] >= s0) && (woff[ln + 1] <= s1);
        if (interior) Z1[(size_t)n * DD + f] = sum;
        else atomicAdd(&Z1[(size_t)n * DD + f], sum);
    }
}

// ---- head via MFMA; scatters exp(val) to out[e]; fused per-node denom ----
__global__ __launch_bounds__(256) void k_head3m(
    const EdgeRec* __restrict__ rec, const int* __restrict__ offs, const int* __restrict__ nstart,
    const float* __restrict__ pre, const float* __restrict__ fold,
    const unsigned* __restrict__ fragu, const float* __restrict__ hb2,
    const float* __restrict__ hw3, const float* __restrict__ hb3, const float* __restrict__ g1,
    const float* __restrict__ g2, float* __restrict__ out, float* __restrict__ denom, int nE) {
    __shared__ float evs[256];
    __shared__ int woff[260];
    __shared__ int snode[BLK];
    __shared__ int sh2[2];
    int tid = threadIdx.x, b = blockIdx.x;
    int s0 = b * BLK, s1 = min(s0 + BLK, nE);
    if (tid == 0) {
        int nlo = nstart[b];
        sh2[0] = nlo;
        sh2[1] = nstart[b + 1] - nlo + 1;
    }
    evs[tid] = 0.f;
    snode[tid] = 0;
    __syncthreads();
    int nlo = sh2[0], nwin = sh2[1];
    for (int i = tid; i < nwin + 1; i += 256) woff[i] = offs[nlo + i];
    __syncthreads();
    for (int t = tid; t < nwin; t += 256) {
        int lo = max(woff[t], s0), hi = min(woff[t + 1], s1);
        for (int j = lo; j < hi; ++j) snode[j - s0] = t;
    }
    __syncthreads();

    int l = tid & 63, g = l >> 4, e = l & 15, wv = tid >> 6;
    const uint4* fb = (const uint4*)fragu;
    H8 WA0, WA1, WE0, WE1, H0, H1;
    WA0.u4 = fb[128 + l];
    WA1.u4 = fb[192 + l];
    WE0.u4 = fb[256 + l];
    WE1.u4 = fb[320 + l];
    H0.u4 = fb[384 + l];
    H1.u4 = fb[448 + l];
    f32x4 cua = ld4(pre + 64 + 8 * g), cub = ld4(pre + 64 + 8 * g + 4);
    f32x4 cha = ld4(pre + 128 + 8 * g), chb = ld4(pre + 128 + 8 * g + 4);
    f32x4 dha = ld4(fold + 5248 + 8 * g), dhb = ld4(fold + 5248 + 8 * g + 4);
    f32x4 hb2a = ld4(hb2 + 4 * g), hb2b = ld4(hb2 + 16 + 4 * g);
    f32x4 h3a = ld4(hw3 + 4 * g), h3b = ld4(hw3 + 16 + 4 * g);
    float hb3s = hb3[0];

    for (int c = 0; c < 4; ++c) {
        int ls = wv * 64 + c * 16 + e;
        int slot = s0 + ls;
        int sc = min(slot, nE - 1);
        EdgeRec r = rec[sc];
        float a = r.a;
        int n = nlo + snode[ls];
        const float* g1p = g1 + (size_t)n * DD + 8 * g;
        f32x4 ma = lrelu4(a * cua + ld4(g1p));
        f32x4 mb = lrelu4(a * cub + ld4(g1p + 4));
        H8 B;
        B.u[0] = pkrtz(ma[0], ma[1]);
        B.u[1] = pkrtz(ma[2], ma[3]);
        B.u[2] = pkrtz(mb[0], mb[1]);
        B.u[3] = pkrtz(mb[2], mb[3]);
        const float* g2p = g2 + (size_t)n * DD + 8 * g;
        f32x4 z0 = ld4(g2p), z1 = ld4(g2p + 4);  // C_in = g2 (incl. bias)
        z0 = __builtin_amdgcn_mfma_f32_16x16x32_f16(WA0.h, B.h, z0, 0, 0, 0);
        z1 = __builtin_amdgcn_mfma_f32_16x16x32_f16(WA1.h, B.h, z1, 0, 0, 0);
        z0 = lrelu4(z0);
        z1 = lrelu4(z1);
        B.u[0] = pkrtz(z0[0], z0[1]);
        B.u[1] = pkrtz(z0[2], z0[3]);
        B.u[2] = pkrtz(z1[0], z1[1]);
        B.u[3] = pkrtz(z1[2], z1[3]);
        f32x4 v0 = a * cha + dha, v1 = a * chb + dhb;
        v0 = __builtin_amdgcn_mfma_f32_16x16x32_f16(WE0.h, B.h, v0, 0, 0, 0);
        v1 = __builtin_amdgcn_mfma_f32_16x16x32_f16(WE1.h, B.h, v1, 0, 0, 0);
        v0 = lrelu4(v0);
        v1 = lrelu4(v1);
        B.u[0] = pkrtz(v0[0], v0[1]);
        B.u[1] = pkrtz(v0[2], v0[3]);
        B.u[2] = pkrtz(v1[0], v1[1]);
        B.u[3] = pkrtz(v1[2], v1[3]);
        f32x4 w0 = hb2a, w1 = hb2b;
        w0 = __builtin_amdgcn_mfma_f32_16x16x32_f16(H0.h, B.h, w0, 0, 0, 0);
        w1 = __builtin_amdgcn_mfma_f32_16x16x32_f16(H1.h, B.h, w1, 0, 0, 0);
        w0 = lrelu4(w0);
        w1 = lrelu4(w1);
        f32x4 t = w0 * h3a + w1 * h3b;
        float val = t[0] + t[1] + t[2] + t[3];
        val += __shfl_xor(val, 16, 64);
        val += __shfl_xor(val, 32, 64);
        float exv = __expf(val + hb3s);  // max-shift dropped: logits O(1)
        if (g == 0 && slot < s1) {
            out[r.e] = exv;  // scatter numerator; k_div normalizes in place
            evs[ls] = exv;
        }
    }
    __syncthreads();
    for (int t = tid; t < nwin; t += 256) {
        int lo = max(woff[t], s0), hi = min(woff[t + 1], s1);
        if (lo >= hi) continue;
        float sum = 0.f;
        for (int j = lo; j < hi; ++j) sum += evs[j - s0];
        int n = nlo + t;
        bool interior = (woff[t] >= s0) && (woff[t + 1] <= s1);
        if (interior) denom[n] = sum;
        else atomicAdd(&denom[n], sum);
    }
}

// ---- div: out[e] /= denom[ei[e]] (fully coalesced; denom is L2-resident) ----
__global__ __launch_bounds__(256) void k_div(const int* __restrict__ ei,
                                             const float* __restrict__ denom,
                                             float* __restrict__ out, int nE) {
    int e = blockIdx.x * 256 + threadIdx.x;
    if (e >= nE) return;
    out[e] = out[e] / denom[ei[e]];
}

extern "C" void kernel_launch(void* const* d_in, const int* in_sizes, int n_in, void* d_out,
                              int out_size, void* d_ws, size_t ws_size, hipStream_t stream) {
    const float* ea = (const float*)d_in[0];
    const int* ei = (const int*)d_in[1];
    const float* w_in = (const float*)d_in[2];
    const float* b_in = (const float*)d_in[3];
    const float* tw1 = (const float*)d_in[4];
    const float* tb1 = (const float*)d_in[5];
    const float* tw2 = (const float*)d_in[6];
    const float* tb2 = (const float*)d_in[7];
    const float* uw1 = (const float*)d_in[8];
    const float* ub1 = (const float*)d_in[9];
    const float* uw2 = (const float*)d_in[10];
    const float* ub2 = (const float*)d_in[11];
    const float* hw1 = (const float*)d_in[12];
    const float* hb1 = (const float*)d_in[13];
    const float* hw2 = (const float*)d_in[14];
    const float* hb2 = (const float*)d_in[15];
    const float* hw3 = (const float*)d_in[16];
    const float* hb3 = (const float*)d_in[17];

    const int nE = in_sizes[0];
    const int gridB = (nE + BLK - 1) / BLK;

    char* w = (char*)d_ws;
    size_t pos = 0;
    auto alloc = [&](size_t bytes) -> void* {
        void* p = w + pos;
        pos = (pos + bytes + 255) & ~(size_t)255;
        return p;
    };
    int* cnt = (int*)alloc((size_t)NN * 4);       // node counts -> cursors
    int* bh = (int*)alloc((size_t)NB * 4);        // bucket counts -> cursors
    int* offs = (int*)alloc((size_t)(NN + 1) * 4);
    int* boff = (int*)alloc((size_t)(NB + 1) * 4);
    int* nstart = (int*)alloc((size_t)(gridB + 1) * 4);
    EdgeRec* rec = (EdgeRec*)alloc((size_t)nE * sizeof(EdgeRec));
    // region R (aliased by staging during fill):
    float* M0 = (float*)alloc((size_t)NN * DD * 4);
    float* Z1 = (float*)alloc((size_t)NN * DD * 4);
    float* denom = (float*)alloc((size_t)NN * 4);
    float* g1 = (float*)alloc((size_t)NN * DD * 4);
    float* g2 = (float*)alloc((size_t)NN * DD * 4);
    float* pre = (float*)alloc(6 * 32 * 4);
    float* fold = (float*)alloc((5 * 1024 + 5 * 32) * 4);
    unsigned* fragu = (unsigned*)alloc(2048 * 4);

    // staging aliases R (dead until after fillB): sa|se|ss = 24 MB < 25.8 MB
    float* sa = M0;
    int* se = (int*)M0 + (size_t)nE;
    int* ss = (int*)M0 + (size_t)2 * nE;

    // zero cnt..bh (contiguous in alloc order)
    hipMemsetAsync(cnt, 0, (size_t)((char*)offs - (char*)cnt), stream);

    int gridE = (nE + 255) / 256;
    int gridNF = (NN * DD + 255) / 256;

    k_prep<<<1, 192, 0, stream>>>(w_in, b_in, tw1, tb1, uw1, ub1, hw1, hb1, pre);
    k_prep2<<<1, 256, 0, stream>>>(tw1, tb1, tw2, tb2, uw1, ub1, uw2, ub2, hw1, hw2, pre, fold,
                                   fragu);
    k_hist2<<<gridE, 256, 0, stream>>>(ei, cnt, bh, nE);
    k_scan<<<1, 1024, 0, stream>>>(cnt, offs, NN);
    k_scan<<<1, 1024, 0, stream>>>(bh, boff, NB);
    k_fillA<<<gridE, 256, 0, stream>>>(ei, ea, bh, sa, se, ss, nE);
    k_fillB<<<gridE, 256, 0, stream>>>(sa, se, ss, cnt, rec, nE);
    k_bstart<<<(gridB + 256) / 256, 256, 0, stream>>>(offs, nstart, gridB, nE);

    // staging dead; now zero M0|Z1|denom (contiguous in alloc order)
    hipMemsetAsync(M0, 0, (size_t)((char*)g1 - (char*)M0), stream);

    // layer 0
    k_accum0f<<<gridB, 256, 0, stream>>>(rec, offs, nstart, pre, M0, nE);
    k_gnode<<<gridNF, 256, 0, stream>>>(M0, fold + 2048, fold + 5152, pre + 96, offs, g1);

    // layer 1
    k_z1m<<<gridB, 256, 0, stream>>>(rec, offs, nstart, pre, fold, fragu, g1, Z1, nE);
    k_gnode<<<gridNF, 256, 0, stream>>>(Z1, fold + 3072, fold + 5184, fold + 5216, offs, g2);

    // head + denom, then coalesced divide
    k_head3m<<<gridB, 256, 0, stream>>>(rec, offs, nstart, pre, fold, fragu, hb2, hw3, hb3, g1, g2,
                                        (float*)d_out, denom, nE);
    k_div<<<gridE, 256, 0, stream>>>(ei, denom, (float*)d_out, nE);
}

// Round 14
// 676.174 us; speedup vs baseline: 2.8743x; 2.8743x over previous
//
#include <hip/hip_runtime.h>

#define NN 50000
#define DD 32
#define BLK 256

typedef float f32x4 __attribute__((ext_vector_type(4)));
typedef _Float16 f16x8 __attribute__((ext_vector_type(8)));
typedef __fp16 fp16x2 __attribute__((ext_vector_type(2)));

struct __align__(8) EdgeRec {
    float a;
    int e;  // original edge id
};

union H8 {
    f16x8 h;
    unsigned u[4];
    uint4 u4;
};

__device__ __forceinline__ float lrelu(float x) { return fmaxf(x, 0.01f * x); }

__device__ __forceinline__ f32x4 lrelu4(f32x4 v) {
    f32x4 r;
    r[0] = fmaxf(v[0], 0.01f * v[0]);
    r[1] = fmaxf(v[1], 0.01f * v[1]);
    r[2] = fmaxf(v[2], 0.01f * v[2]);
    r[3] = fmaxf(v[3], 0.01f * v[3]);
    return r;
}

__device__ __forceinline__ unsigned pkrtz(float a, float b) {
    union {
        fp16x2 h;
        unsigned u;
    } x;
    x.h = __builtin_amdgcn_cvt_pkrtz(a, b);
    return x.u;
}

__device__ __forceinline__ f32x4 ld4(const float* __restrict__ p) {
    return *(const f32x4*)p;
}

__device__ __forceinline__ void lds_copy(float* dst, const float* __restrict__ src, int n) {
    for (int i = threadIdx.x; i < n; i += blockDim.x) dst[i] = src[i];
}

// ---------------- CSR build (single-pass: 50k-way counters, low contention) ----------------
__global__ __launch_bounds__(256) void k_hist(const int* __restrict__ ei, int* __restrict__ cnt,
                                              int nE) {
    int e = blockIdx.x * 256 + threadIdx.x;
    if (e < nE) atomicAdd(&cnt[ei[e]], 1);
}

__global__ __launch_bounds__(1024) void k_scan(int* __restrict__ cnt_cur, int* __restrict__ off,
                                               int nN) {
    __shared__ int part[1024];
    int t = threadIdx.x;
    const int CH = (nN + 1023) / 1024;
    int beg = t * CH, end = min(beg + CH, nN);
    int sum = 0;
    for (int i = beg; i < end; ++i) sum += cnt_cur[i];
    part[t] = sum;
    __syncthreads();
    for (int ofs = 1; ofs < 1024; ofs <<= 1) {
        int v = (t >= ofs) ? part[t - ofs] : 0;
        __syncthreads();
        part[t] += v;
        __syncthreads();
    }
    int run = (t == 0) ? 0 : part[t - 1];
    for (int i = beg; i < end; ++i) {
        int c = cnt_cur[i];
        off[i] = run;
        cnt_cur[i] = run;  // cursor copy
        run += c;
    }
    if (t == 1023) off[nN] = part[1023];
}

// rec[pos] = {a, e}; random 8B scatter paid once (write-amp accepted; 391-bucket
// binning attempt regressed 3x on cursor contention — see round-12 post-mortem)
__global__ __launch_bounds__(256) void k_fill(const int* __restrict__ ei,
                                              const float* __restrict__ ea, int* __restrict__ cur,
                                              EdgeRec* __restrict__ rec, int nE) {
    int e = blockIdx.x * 256 + threadIdx.x;
    if (e >= nE) return;
    int src = ei[e];
    int pos = atomicAdd(&cur[src], 1);
    reinterpret_cast<int2*>(rec)[pos] = make_int2(__float_as_int(ea[e]), e);
}

// nstart[b] = node containing slot min(b*BLK, nE-1)
__global__ __launch_bounds__(256) void k_bstart(const int* __restrict__ offs,
                                                int* __restrict__ nstart, int nB, int nE) {
    int b = blockIdx.x * 256 + threadIdx.x;
    if (b > nB) return;
    int s = min(b * BLK, nE - 1);
    int lo = 0, hi = NN - 1;
    while (lo < hi) {
        int mid = (lo + hi + 1) >> 1;
        if (offs[mid] <= s) lo = mid;
        else hi = mid - 1;
    }
    nstart[b] = lo;
}

// ---- prep: affine-in-a folds. pre = [c1,d1,cu,du,ch,dh] (6x32) ----
__global__ __launch_bounds__(192) void k_prep(const float* __restrict__ w_in,
                                              const float* __restrict__ b_in,
                                              const float* __restrict__ tw1,
                                              const float* __restrict__ tb1,
                                              const float* __restrict__ uw1,
                                              const float* __restrict__ ub1,
                                              const float* __restrict__ hw1,
                                              const float* __restrict__ hb1,
                                              float* __restrict__ pre) {
    int t = threadIdx.x;
    int which = t >> 5, f = t & 31;
    if (which >= 6) return;
    const float* W = (which < 2) ? tw1 : (which < 4) ? uw1 : hw1;
    const float* x = (which & 1) ? b_in : w_in;
    const float* badd = (which == 1) ? tb1 : (which == 3) ? ub1 : (which == 5) ? hb1 : nullptr;
    float s = badd ? badd[f] : 0.f;
    for (int k = 0; k < 32; ++k) s = fmaf(x[k], W[k * 32 + f], s);
    pre[which * 32 + f] = s;
}

// ---- prep2: fold adjacent linear maps + pack f16 MFMA A-fragments ----
// fold: [0)WA [1024)WB [2048)WC [3072)WD [4096)WE [5120)vB [5152)vC [5184)vD
//       [5216)addg2 [5248)dh2
// fragu: A-frags for {0=WB,1=WA,2=WE,3=hw2}, 2 tiles each; phi = S-perm for m<3.
__global__ __launch_bounds__(256) void k_prep2(
    const float* __restrict__ tw1, const float* __restrict__ tb1, const float* __restrict__ tw2,
    const float* __restrict__ tb2, const float* __restrict__ uw1, const float* __restrict__ ub1,
    const float* __restrict__ uw2, const float* __restrict__ ub2, const float* __restrict__ hw1,
    const float* __restrict__ hw2, const float* __restrict__ pre, float* __restrict__ fold,
    unsigned* __restrict__ fragu) {
    for (int e = threadIdx.x; e < 5 * 1024 + 5 * 32; e += 256) {
        if (e < 5120) {
            int m = e >> 10, r = e & 1023, i = r >> 5, j = r & 31;
            const float* A;
            const float* B;
            switch (m) {
                case 0: A = uw2;        B = uw1 + 2048; break;
                case 1: A = uw2;        B = tw1 + 1024; break;
                case 2: A = tw2;        B = uw1 + 1024; break;
                case 3: A = tw2 + 1024; B = uw1 + 3072; break;
                default: A = uw2 + 1024; B = hw1 + 1024; break;
            }
            float s = 0.f;
            for (int k = 0; k < 32; ++k) s = fmaf(A[i * 32 + k], B[k * 32 + j], s);
            fold[e] = s;
        } else {
            int r = e - 5120;
            int v = r >> 5, f = r & 31;
            const float* x;
            const float* B;
            float s;
            switch (v) {
                case 0: x = ub2;      B = tw1 + 1024; s = tb1[32 + f]; break;  // vB
                case 1: x = tb2;      B = uw1 + 1024; s = 0.f;         break;  // vC
                case 2: x = tb2 + 32; B = uw1 + 3072; s = 0.f;         break;  // vD
                case 3: x = ub2;      B = uw1 + 2048; s = ub1[32 + f]; break;  // addg2
                default: x = ub2 + 32; B = hw1 + 1024; s = pre[160 + f]; break;  // dh2
            }
            for (int k = 0; k < 32; ++k) s = fmaf(x[k], B[k * 32 + f], s);
            fold[e] = s;
        }
    }
    __syncthreads();
    for (int idx = threadIdx.x; idx < 2048; idx += 256) {
        int d = idx & 3;
        int l = (idx >> 2) & 63;
        int T = (idx >> 8) & 1;
        int m = idx >> 9;
        int row = 16 * T + (l & 15);
        int k0 = ((l >> 4) << 3) + 2 * d;
        const float* W = (m == 0) ? fold + 1024 : (m == 1) ? fold : (m == 2) ? fold + 4096 : hw2;
        int phi = (m == 3) ? row : (((row >> 2) & 3) * 8 + ((row >> 4) << 2) + (row & 3));
        union {
            _Float16 h[2];
            unsigned u;
        } P;
        P.h[0] = (_Float16)W[k0 * 32 + phi];
        P.h[1] = (_Float16)W[(k0 + 1) * 32 + phi];
        fragu[idx] = P.u;
    }
}

// ---- fused accum0: per-edge v=lrelu(a*c1+d1), block-local segment-sum -> M0 ----
__global__ __launch_bounds__(256) void k_accum0f(const EdgeRec* __restrict__ rec,
                                                 const int* __restrict__ offs,
                                                 const int* __restrict__ nstart,
                                                 const float* __restrict__ pre,
                                                 float* __restrict__ M0, int nE) {
    __shared__ float zs[256 * 33];
    __shared__ int woff[260];
    __shared__ int sh2[2];
    int tid = threadIdx.x, b = blockIdx.x;
    int s0 = b * BLK, s1 = min(s0 + BLK, nE);
    if (tid == 0) {
        int nlo = nstart[b];
        sh2[0] = nlo;
        sh2[1] = nstart[b + 1] - nlo + 1;
    }
    __syncthreads();
    int nlo = sh2[0], nwin = sh2[1];
    for (int i = tid; i < nwin + 1; i += 256) woff[i] = offs[nlo + i];
    int s = s0 + tid;
    if (s < s1) {
        float a = rec[s].a;
#pragma unroll
        for (int f = 0; f < DD; ++f) zs[tid * 33 + f] = lrelu(fmaf(a, pre[f], pre[32 + f]));
    }
    __syncthreads();
    for (int t = tid; t < nwin * DD; t += 256) {
        int ln = t >> 5, f = t & 31;
        int lo = max(woff[ln], s0), hi = min(woff[ln + 1], s1);
        if (lo >= hi) continue;
        float sum = 0.f;
        for (int j = lo; j < hi; ++j) sum += zs[(j - s0) * 33 + f];
        int n = nlo + ln;
        bool interior = (woff[ln] >= s0) && (woff[ln + 1] <= s1);
        if (interior) M0[(size_t)n * DD + f] = sum;
        else atomicAdd(&M0[(size_t)n * DD + f], sum);
    }
}

// ---- gnode: g[n] = addv + deg*dv + M[n]@W ----
__global__ __launch_bounds__(256) void k_gnode(const float* __restrict__ M,
                                               const float* __restrict__ W,
                                               const float* __restrict__ dv,
                                               const float* __restrict__ addv,
                                               const int* __restrict__ off, float* __restrict__ g) {
    __shared__ float LW[1088];
    lds_copy(LW, W, 1024);
    lds_copy(LW + 1024, dv, 32);
    lds_copy(LW + 1056, addv, 32);
    __syncthreads();
    int tid = blockIdx.x * 256 + threadIdx.x;
    int n = tid >> 5, f = tid & 31;
    if (n >= NN) return;
    float deg = (float)(off[n + 1] - off[n]);
    const float* srow = M + (size_t)n * DD;
    float acc = fmaf(deg, LW[1024 + f], LW[1056 + f]);
    for (int k = 0; k < 32; ++k) acc = fmaf(srow[k], LW[k * 32 + f], acc);
    g[(size_t)n * DD + f] = acc;
}

// ---- z1 via MFMA; src derived from woff (snode map) ----
__global__ __launch_bounds__(256) void k_z1m(const EdgeRec* __restrict__ rec,
                                             const int* __restrict__ offs,
                                             const int* __restrict__ nstart,
                                             const float* __restrict__ pre,
                                             const float* __restrict__ fold,
                                             const unsigned* __restrict__ fragu,
                                             const float* __restrict__ g1, float* __restrict__ Z1,
                                             int nE) {
    __shared__ __align__(16) float zs[256 * 36];
    __shared__ int woff[260];
    __shared__ int snode[BLK];
    __shared__ int sh2[2];
    int tid = threadIdx.x, b = blockIdx.x;
    int s0 = b * BLK, s1 = min(s0 + BLK, nE);
    if (tid == 0) {
        int nlo = nstart[b];
        sh2[0] = nlo;
        sh2[1] = nstart[b + 1] - nlo + 1;
    }
    snode[tid] = 0;
    __syncthreads();
    int nlo = sh2[0], nwin = sh2[1];
    for (int i = tid; i < nwin + 1; i += 256) woff[i] = offs[nlo + i];
    __syncthreads();
    for (int t = tid; t < nwin; t += 256) {
        int lo = max(woff[t], s0), hi = min(woff[t + 1], s1);
        for (int j = lo; j < hi; ++j) snode[j - s0] = t;
    }
    __syncthreads();

    int l = tid & 63, g = l >> 4, e = l & 15, wv = tid >> 6;
    const uint4* fb = (const uint4*)fragu;
    H8 WB0, WB1;
    WB0.u4 = fb[0 + l];
    WB1.u4 = fb[64 + l];
    f32x4 cua = ld4(pre + 64 + 8 * g), cub = ld4(pre + 64 + 8 * g + 4);
    f32x4 vBa = ld4(fold + 5120 + 8 * g), vBb = ld4(fold + 5120 + 8 * g + 4);

    for (int c = 0; c < 4; ++c) {
        int ls = wv * 64 + c * 16 + e;
        int slot = s0 + ls;
        int sc = min(slot, nE - 1);
        float a = rec[sc].a;
        int n = nlo + snode[ls];
        const float* g1p = g1 + (size_t)n * DD + 8 * g;
        f32x4 ma = lrelu4(a * cua + ld4(g1p));
        f32x4 mb = lrelu4(a * cub + ld4(g1p + 4));
        H8 B;
        B.u[0] = pkrtz(ma[0], ma[1]);
        B.u[1] = pkrtz(ma[2], ma[3]);
        B.u[2] = pkrtz(mb[0], mb[1]);
        B.u[3] = pkrtz(mb[2], mb[3]);
        f32x4 z0 = __builtin_amdgcn_mfma_f32_16x16x32_f16(WB0.h, B.h, vBa, 0, 0, 0);
        f32x4 z1 = __builtin_amdgcn_mfma_f32_16x16x32_f16(WB1.h, B.h, vBb, 0, 0, 0);
        z0 = lrelu4(z0);
        z1 = lrelu4(z1);
        *(f32x4*)&zs[ls * 36 + 8 * g] = z0;
        *(f32x4*)&zs[ls * 36 + 8 * g + 4] = z1;
    }
    __syncthreads();
    for (int t = tid; t < nwin * DD; t += 256) {
        int ln = t >> 5, f = t & 31;
        int lo = max(woff[ln], s0), hi = min(woff[ln + 1], s1);
        if (lo >= hi) continue;
        float sum = 0.f;
        for (int j = lo; j < hi; ++j) sum += zs[(j - s0) * 36 + f];
        int n = nlo + ln;
        bool interior = (woff[ln] >= s0) && (woff[ln + 1] <= s1);
        if (interior) Z1[(size_t)n * DD + f] = sum;
        else atomicAdd(&Z1[(size_t)n * DD + f], sum);
    }
}

// ---- head via MFMA; scatters exp(val) to out[e]; fused per-node denom ----
__global__ __launch_bounds__(256) void k_head3m(
    const EdgeRec* __restrict__ rec, const int* __restrict__ offs, const int* __restrict__ nstart,
    const float* __restrict__ pre, const float* __restrict__ fold,
    const unsigned* __restrict__ fragu, const float* __restrict__ hb2,
    const float* __restrict__ hw3, const float* __restrict__ hb3, const float* __restrict__ g1,
    const float* __restrict__ g2, float* __restrict__ out, float* __restrict__ denom, int nE) {
    __shared__ float evs[256];
    __shared__ int woff[260];
    __shared__ int snode[BLK];
    __shared__ int sh2[2];
    int tid = threadIdx.x, b = blockIdx.x;
    int s0 = b * BLK, s1 = min(s0 + BLK, nE);
    if (tid == 0) {
        int nlo = nstart[b];
        sh2[0] = nlo;
        sh2[1] = nstart[b + 1] - nlo + 1;
    }
    evs[tid] = 0.f;
    snode[tid] = 0;
    __syncthreads();
    int nlo = sh2[0], nwin = sh2[1];
    for (int i = tid; i < nwin + 1; i += 256) woff[i] = offs[nlo + i];
    __syncthreads();
    for (int t = tid; t < nwin; t += 256) {
        int lo = max(woff[t], s0), hi = min(woff[t + 1], s1);
        for (int j = lo; j < hi; ++j) snode[j - s0] = t;
    }
    __syncthreads();

    int l = tid & 63, g = l >> 4, e = l & 15, wv = tid >> 6;
    const uint4* fb = (const uint4*)fragu;
    H8 WA0, WA1, WE0, WE1, H0, H1;
    WA0.u4 = fb[128 + l];
    WA1.u4 = fb[192 + l];
    WE0.u4 = fb[256 + l];
    WE1.u4 = fb[320 + l];
    H0.u4 = fb[384 + l];
    H1.u4 = fb[448 + l];
    f32x4 cua = ld4(pre + 64 + 8 * g), cub = ld4(pre + 64 + 8 * g + 4);
    f32x4 cha = ld4(pre + 128 + 8 * g), chb = ld4(pre + 128 + 8 * g + 4);
    f32x4 dha = ld4(fold + 5248 + 8 * g), dhb = ld4(fold + 5248 + 8 * g + 4);
    f32x4 hb2a = ld4(hb2 + 4 * g), hb2b = ld4(hb2 + 16 + 4 * g);
    f32x4 h3a = ld4(hw3 + 4 * g), h3b = ld4(hw3 + 16 + 4 * g);
    float hb3s = hb3[0];

    for (int c = 0; c < 4; ++c) {
        int ls = wv * 64 + c * 16 + e;
        int slot = s0 + ls;
        int sc = min(slot, nE - 1);
        EdgeRec r = rec[sc];
        float a = r.a;
        int n = nlo + snode[ls];
        const float* g1p = g1 + (size_t)n * DD + 8 * g;
        f32x4 ma = lrelu4(a * cua + ld4(g1p));
        f32x4 mb = lrelu4(a * cub + ld4(g1p + 4));
        H8 B;
        B.u[0] = pkrtz(ma[0], ma[1]);
        B.u[1] = pkrtz(ma[2], ma[3]);
        B.u[2] = pkrtz(mb[0], mb[1]);
        B.u[3] = pkrtz(mb[2], mb[3]);
        const float* g2p = g2 + (size_t)n * DD + 8 * g;
        f32x4 z0 = ld4(g2p), z1 = ld4(g2p + 4);  // C_in = g2 (incl. bias)
        z0 = __builtin_amdgcn_mfma_f32_16x16x32_f16(WA0.h, B.h, z0, 0, 0, 0);
        z1 = __builtin_amdgcn_mfma_f32_16x16x32_f16(WA1.h, B.h, z1, 0, 0, 0);
        z0 = lrelu4(z0);
        z1 = lrelu4(z1);
        B.u[0] = pkrtz(z0[0], z0[1]);
        B.u[1] = pkrtz(z0[2], z0[3]);
        B.u[2] = pkrtz(z1[0], z1[1]);
        B.u[3] = pkrtz(z1[2], z1[3]);
        f32x4 v0 = a * cha + dha, v1 = a * chb + dhb;
        v0 = __builtin_amdgcn_mfma_f32_16x16x32_f16(WE0.h, B.h, v0, 0, 0, 0);
        v1 = __builtin_amdgcn_mfma_f32_16x16x32_f16(WE1.h, B.h, v1, 0, 0, 0);
        v0 = lrelu4(v0);
        v1 = lrelu4(v1);
        B.u[0] = pkrtz(v0[0], v0[1]);
        B.u[1] = pkrtz(v0[2], v0[3]);
        B.u[2] = pkrtz(v1[0], v1[1]);
        B.u[3] = pkrtz(v1[2], v1[3]);
        f32x4 w0 = hb2a, w1 = hb2b;
        w0 = __builtin_amdgcn_mfma_f32_16x16x32_f16(H0.h, B.h, w0, 0, 0, 0);
        w1 = __builtin_amdgcn_mfma_f32_16x16x32_f16(H1.h, B.h, w1, 0, 0, 0);
        w0 = lrelu4(w0);
        w1 = lrelu4(w1);
        f32x4 t = w0 * h3a + w1 * h3b;
        float val = t[0] + t[1] + t[2] + t[3];
        val += __shfl_xor(val, 16, 64);
        val += __shfl_xor(val, 32, 64);
        float exv = __expf(val + hb3s);  // max-shift dropped: logits O(1)
        if (g == 0 && slot < s1) {
            out[r.e] = exv;  // scatter numerator; k_div normalizes in place
            evs[ls] = exv;
        }
    }
    __syncthreads();
    for (int t = tid; t < nwin; t += 256) {
        int lo = max(woff[t], s0), hi = min(woff[t + 1], s1);
        if (lo >= hi) continue;
        float sum = 0.f;
        for (int j = lo; j < hi; ++j) sum += evs[j - s0];
        int n = nlo + t;
        bool interior = (woff[t] >= s0) && (woff[t + 1] <= s1);
        if (interior) denom[n] = sum;
        else atomicAdd(&denom[n], sum);
    }
}

// ---- div: out[e] /= denom[ei[e]] (coalesced; denom 200KB, L2-resident) ----
__global__ __launch_bounds__(256) void k_div(const int* __restrict__ ei,
                                             const float* __restrict__ denom,
                                             float* __restrict__ out, int nE) {
    int e = blockIdx.x * 256 + threadIdx.x;
    if (e >= nE) return;
    out[e] = out[e] / denom[ei[e]];
}

extern "C" void kernel_launch(void* const* d_in, const int* in_sizes, int n_in, void* d_out,
                              int out_size, void* d_ws, size_t ws_size, hipStream_t stream) {
    const float* ea = (const float*)d_in[0];
    const int* ei = (const int*)d_in[1];
    const float* w_in = (const float*)d_in[2];
    const float* b_in = (const float*)d_in[3];
    const float* tw1 = (const float*)d_in[4];
    const float* tb1 = (const float*)d_in[5];
    const float* tw2 = (const float*)d_in[6];
    const float* tb2 = (const float*)d_in[7];
    const float* uw1 = (const float*)d_in[8];
    const float* ub1 = (const float*)d_in[9];
    const float* uw2 = (const float*)d_in[10];
    const float* ub2 = (const float*)d_in[11];
    const float* hw1 = (const float*)d_in[12];
    const float* hb1 = (const float*)d_in[13];
    const float* hw2 = (const float*)d_in[14];
    const float* hb2 = (const float*)d_in[15];
    const float* hw3 = (const float*)d_in[16];
    const float* hb3 = (const float*)d_in[17];

    const int nE = in_sizes[0];
    const int gridB = (nE + BLK - 1) / BLK;

    char* w = (char*)d_ws;
    size_t pos = 0;
    auto alloc = [&](size_t bytes) -> void* {
        void* p = w + pos;
        pos = (pos + bytes + 255) & ~(size_t)255;
        return p;
    };
    int* cnt = (int*)alloc((size_t)NN * 4);  // node counts -> cursors
    int* offs = (int*)alloc((size_t)(NN + 1) * 4);
    int* nstart = (int*)alloc((size_t)(gridB + 1) * 4);
    EdgeRec* rec = (EdgeRec*)alloc((size_t)nE * sizeof(EdgeRec));
    float* M0 = (float*)alloc((size_t)NN * DD * 4);  // M0|Z1|denom contiguous -> one memset
    float* Z1 = (float*)alloc((size_t)NN * DD * 4);
    float* denom = (float*)alloc((size_t)NN * 4);
    float* g1 = (float*)alloc((size_t)NN * DD * 4);
    float* g2 = (float*)alloc((size_t)NN * DD * 4);
    float* pre = (float*)alloc(6 * 32 * 4);
    float* fold = (float*)alloc((5 * 1024 + 5 * 32) * 4);
    unsigned* fragu = (unsigned*)alloc(2048 * 4);

    hipMemsetAsync(cnt, 0, (size_t)NN * 4, stream);
    hipMemsetAsync(M0, 0, (size_t)((char*)g1 - (char*)M0), stream);

    int gridE = (nE + 255) / 256;
    int gridNF = (NN * DD + 255) / 256;

    k_prep<<<1, 192, 0, stream>>>(w_in, b_in, tw1, tb1, uw1, ub1, hw1, hb1, pre);
    k_prep2<<<1, 256, 0, stream>>>(tw1, tb1, tw2, tb2, uw1, ub1, uw2, ub2, hw1, hw2, pre, fold,
                                   fragu);
    k_hist<<<gridE, 256, 0, stream>>>(ei, cnt, nE);
    k_scan<<<1, 1024, 0, stream>>>(cnt, offs, NN);
    k_fill<<<gridE, 256, 0, stream>>>(ei, ea, cnt, rec, nE);
    k_bstart<<<(gridB + 256) / 256, 256, 0, stream>>>(offs, nstart, gridB, nE);

    // layer 0
    k_accum0f<<<gridB, 256, 0, stream>>>(rec, offs, nstart, pre, M0, nE);
    k_gnode<<<gridNF, 256, 0, stream>>>(M0, fold + 2048, fold + 5152, pre + 96, offs, g1);

    // layer 1
    k_z1m<<<gridB, 256, 0, stream>>>(rec, offs, nstart, pre, fold, fragu, g1, Z1, nE);
    k_gnode<<<gridNF, 256, 0, stream>>>(Z1, fold + 3072, fold + 5184, fold + 5216, offs, g2);

    // head + denom, then coalesced divide
    k_head3m<<<gridB, 256, 0, stream>>>(rec, offs, nstart, pre, fold, fragu, hb2, hw3, hb3, g1, g2,
                                        (float*)d_out, denom, nE);
    k_div<<<gridE, 256, 0, stream>>>(ei, denom, (float*)d_out, nE);
}

// Round 15
// 627.463 us; speedup vs baseline: 3.0975x; 1.0776x over previous
//
#include <hip/hip_runtime.h>

#define NN 50000
#define DD 32
#define BLK 256
#define NSLICE 256  // blocks per chunk in fillB; grid = 8*NSLICE

typedef float f32x4 __attribute__((ext_vector_type(4)));
typedef _Float16 f16x8 __attribute__((ext_vector_type(8)));
typedef __fp16 fp16x2 __attribute__((ext_vector_type(2)));

struct __align__(8) EdgeRec {
    float a;
    int e;  // original edge id
};

union H8 {
    f16x8 h;
    unsigned u[4];
    uint4 u4;
};

__device__ __forceinline__ float lrelu(float x) { return fmaxf(x, 0.01f * x); }

__device__ __forceinline__ f32x4 lrelu4(f32x4 v) {
    f32x4 r;
    r[0] = fmaxf(v[0], 0.01f * v[0]);
    r[1] = fmaxf(v[1], 0.01f * v[1]);
    r[2] = fmaxf(v[2], 0.01f * v[2]);
    r[3] = fmaxf(v[3], 0.01f * v[3]);
    return r;
}

__device__ __forceinline__ unsigned pkrtz(float a, float b) {
    union {
        fp16x2 h;
        unsigned u;
    } x;
    x.h = __builtin_amdgcn_cvt_pkrtz(a, b);
    return x.u;
}

__device__ __forceinline__ f32x4 ld4(const float* __restrict__ p) {
    return *(const f32x4*)p;
}

__device__ __forceinline__ void lds_copy(float* dst, const float* __restrict__ src, int n) {
    for (int i = threadIdx.x; i < n; i += blockDim.x) dst[i] = src[i];
}

// ---------------- CSR build ----------------
__global__ __launch_bounds__(256) void k_hist(const int* __restrict__ ei, int* __restrict__ cnt,
                                              int nE) {
    int e = blockIdx.x * 256 + threadIdx.x;
    if (e < nE) atomicAdd(&cnt[ei[e]], 1);
}

__global__ __launch_bounds__(1024) void k_scan(int* __restrict__ cnt_cur, int* __restrict__ off,
                                               int nN) {
    __shared__ int part[1024];
    int t = threadIdx.x;
    const int CH = (nN + 1023) / 1024;
    int beg = t * CH, end = min(beg + CH, nN);
    int sum = 0;
    for (int i = beg; i < end; ++i) sum += cnt_cur[i];
    part[t] = sum;
    __syncthreads();
    for (int ofs = 1; ofs < 1024; ofs <<= 1) {
        int v = (t >= ofs) ? part[t - ofs] : 0;
        __syncthreads();
        part[t] += v;
        __syncthreads();
    }
    int run = (t == 0) ? 0 : part[t - 1];
    for (int i = beg; i < end; ++i) {
        int c = cnt_cur[i];
        off[i] = run;
        cnt_cur[i] = run;  // cursor copy
        run += c;
    }
    if (t == 1023) off[nN] = part[1023];
}

// fill pass A: claim slots (50k low-contention cursors); pos[e] written COALESCED
__global__ __launch_bounds__(256) void k_fillA(const int* __restrict__ ei, int* __restrict__ cur,
                                               int* __restrict__ posArr, int nE) {
    int e = blockIdx.x * 256 + threadIdx.x;
    if (e >= nE) return;
    posArr[e] = atomicAdd(&cur[ei[e]], 1);
}

// fill pass B: XCD-affine scatter. chunk = blockIdx&7 -> one XCD (round-robin
// dispatch) owns each 2MB slot-range; its L2 merges all writes to a rec line
// before one eviction (fixes the 8x cross-XCD sector amplification).
__global__ __launch_bounds__(256) void k_fillB(const float* __restrict__ ea,
                                               const int* __restrict__ posArr,
                                               EdgeRec* __restrict__ rec, int nE, int chl) {
    int chunk = blockIdx.x & 7;
    int slice = blockIdx.x >> 3;
    for (int e = slice * 256 + threadIdx.x; e < nE; e += NSLICE * 256) {
        int p = posArr[e];
        if ((p >> chl) == chunk) {
            reinterpret_cast<int2*>(rec)[p] = make_int2(__float_as_int(ea[e]), e);
        }
    }
}

// nstart[b] = node containing slot min(b*BLK, nE-1)
__global__ __launch_bounds__(256) void k_bstart(const int* __restrict__ offs,
                                                int* __restrict__ nstart, int nB, int nE) {
    int b = blockIdx.x * 256 + threadIdx.x;
    if (b > nB) return;
    int s = min(b * BLK, nE - 1);
    int lo = 0, hi = NN - 1;
    while (lo < hi) {
        int mid = (lo + hi + 1) >> 1;
        if (offs[mid] <= s) lo = mid;
        else hi = mid - 1;
    }
    nstart[b] = lo;
}

// ---- prep: affine-in-a folds. pre = [c1,d1,cu,du,ch,dh] (6x32) ----
__global__ __launch_bounds__(192) void k_prep(const float* __restrict__ w_in,
                                              const float* __restrict__ b_in,
                                              const float* __restrict__ tw1,
                                              const float* __restrict__ tb1,
                                              const float* __restrict__ uw1,
                                              const float* __restrict__ ub1,
                                              const float* __restrict__ hw1,
                                              const float* __restrict__ hb1,
                                              float* __restrict__ pre) {
    int t = threadIdx.x;
    int which = t >> 5, f = t & 31;
    if (which >= 6) return;
    const float* W = (which < 2) ? tw1 : (which < 4) ? uw1 : hw1;
    const float* x = (which & 1) ? b_in : w_in;
    const float* badd = (which == 1) ? tb1 : (which == 3) ? ub1 : (which == 5) ? hb1 : nullptr;
    float s = badd ? badd[f] : 0.f;
    for (int k = 0; k < 32; ++k) s = fmaf(x[k], W[k * 32 + f], s);
    pre[which * 32 + f] = s;
}

// ---- prep2: fold adjacent linear maps + pack f16 MFMA A-fragments ----
// fold: [0)WA [1024)WB [2048)WC [3072)WD [4096)WE [5120)vB [5152)vC [5184)vD
//       [5216)addg2 [5248)dh2
// fragu: A-frags for {0=WB,1=WA,2=WE,3=hw2}, 2 tiles each; phi = S-perm for m<3.
__global__ __launch_bounds__(256) void k_prep2(
    const float* __restrict__ tw1, const float* __restrict__ tb1, const float* __restrict__ tw2,
    const float* __restrict__ tb2, const float* __restrict__ uw1, const float* __restrict__ ub1,
    const float* __restrict__ uw2, const float* __restrict__ ub2, const float* __restrict__ hw1,
    const float* __restrict__ hw2, const float* __restrict__ pre, float* __restrict__ fold,
    unsigned* __restrict__ fragu) {
    for (int e = threadIdx.x; e < 5 * 1024 + 5 * 32; e += 256) {
        if (e < 5120) {
            int m = e >> 10, r = e & 1023, i = r >> 5, j = r & 31;
            const float* A;
            const float* B;
            switch (m) {
                case 0: A = uw2;        B = uw1 + 2048; break;
                case 1: A = uw2;        B = tw1 + 1024; break;
                case 2: A = tw2;        B = uw1 + 1024; break;
                case 3: A = tw2 + 1024; B = uw1 + 3072; break;
                default: A = uw2 + 1024; B = hw1 + 1024; break;
            }
            float s = 0.f;
            for (int k = 0; k < 32; ++k) s = fmaf(A[i * 32 + k], B[k * 32 + j], s);
            fold[e] = s;
        } else {
            int r = e - 5120;
            int v = r >> 5, f = r & 31;
            const float* x;
            const float* B;
            float s;
            switch (v) {
                case 0: x = ub2;      B = tw1 + 1024; s = tb1[32 + f]; break;  // vB
                case 1: x = tb2;      B = uw1 + 1024; s = 0.f;         break;  // vC
                case 2: x = tb2 + 32; B = uw1 + 3072; s = 0.f;         break;  // vD
                case 3: x = ub2;      B = uw1 + 2048; s = ub1[32 + f]; break;  // addg2
                default: x = ub2 + 32; B = hw1 + 1024; s = pre[160 + f]; break;  // dh2
            }
            for (int k = 0; k < 32; ++k) s = fmaf(x[k], B[k * 32 + f], s);
            fold[e] = s;
        }
    }
    __syncthreads();
    for (int idx = threadIdx.x; idx < 2048; idx += 256) {
        int d = idx & 3;
        int l = (idx >> 2) & 63;
        int T = (idx >> 8) & 1;
        int m = idx >> 9;
        int row = 16 * T + (l & 15);
        int k0 = ((l >> 4) << 3) + 2 * d;
        const float* W = (m == 0) ? fold + 1024 : (m == 1) ? fold : (m == 2) ? fold + 4096 : hw2;
        int phi = (m == 3) ? row : (((row >> 2) & 3) * 8 + ((row >> 4) << 2) + (row & 3));
        union {
            _Float16 h[2];
            unsigned u;
        } P;
        P.h[0] = (_Float16)W[k0 * 32 + phi];
        P.h[1] = (_Float16)W[(k0 + 1) * 32 + phi];
        fragu[idx] = P.u;
    }
}

// ---- fused accum0: per-edge v=lrelu(a*c1+d1), block-local segment-sum -> M0 ----
__global__ __launch_bounds__(256) void k_accum0f(const EdgeRec* __restrict__ rec,
                                                 const int* __restrict__ offs,
                                                 const int* __restrict__ nstart,
                                                 const float* __restrict__ pre,
                                                 float* __restrict__ M0, int nE) {
    __shared__ float zs[256 * 33];
    __shared__ int woff[260];
    __shared__ int sh2[2];
    int tid = threadIdx.x, b = blockIdx.x;
    int s0 = b * BLK, s1 = min(s0 + BLK, nE);
    if (tid == 0) {
        int nlo = nstart[b];
        sh2[0] = nlo;
        sh2[1] = nstart[b + 1] - nlo + 1;
    }
    __syncthreads();
    int nlo = sh2[0], nwin = sh2[1];
    for (int i = tid; i < nwin + 1; i += 256) woff[i] = offs[nlo + i];
    int s = s0 + tid;
    if (s < s1) {
        float a = rec[s].a;
#pragma unroll
        for (int f = 0; f < DD; ++f) zs[tid * 33 + f] = lrelu(fmaf(a, pre[f], pre[32 + f]));
    }
    __syncthreads();
    for (int t = tid; t < nwin * DD; t += 256) {
        int ln = t >> 5, f = t & 31;
        int lo = max(woff[ln], s0), hi = min(woff[ln + 1], s1);
        if (lo >= hi) continue;
        float sum = 0.f;
        for (int j = lo; j < hi; ++j) sum += zs[(j - s0) * 33 + f];
        int n = nlo + ln;
        bool interior = (woff[ln] >= s0) && (woff[ln + 1] <= s1);
        if (interior) M0[(size_t)n * DD + f] = sum;
        else atomicAdd(&M0[(size_t)n * DD + f], sum);
    }
}

// ---- gnode: g[n] = addv + deg*dv + M[n]@W ----
__global__ __launch_bounds__(256) void k_gnode(const float* __restrict__ M,
                                               const float* __restrict__ W,
                                               const float* __restrict__ dv,
                                               const float* __restrict__ addv,
                                               const int* __restrict__ off, float* __restrict__ g) {
    __shared__ float LW[1088];
    lds_copy(LW, W, 1024);
    lds_copy(LW + 1024, dv, 32);
    lds_copy(LW + 1056, addv, 32);
    __syncthreads();
    int tid = blockIdx.x * 256 + threadIdx.x;
    int n = tid >> 5, f = tid & 31;
    if (n >= NN) return;
    float deg = (float)(off[n + 1] - off[n]);
    const float* srow = M + (size_t)n * DD;
    float acc = fmaf(deg, LW[1024 + f], LW[1056 + f]);
    for (int k = 0; k < 32; ++k) acc = fmaf(srow[k], LW[k * 32 + f], acc);
    g[(size_t)n * DD + f] = acc;
}

// ---- z1 via MFMA; src derived from woff (snode map) ----
__global__ __launch_bounds__(256) void k_z1m(const EdgeRec* __restrict__ rec,
                                             const int* __restrict__ offs,
                                             const int* __restrict__ nstart,
                                             const float* __restrict__ pre,
                                             const float* __restrict__ fold,
                                             const unsigned* __restrict__ fragu,
                                             const float* __restrict__ g1, float* __restrict__ Z1,
                                             int nE) {
    __shared__ __align__(16) float zs[256 * 36];
    __shared__ int woff[260];
    __shared__ int snode[BLK];
    __shared__ int sh2[2];
    int tid = threadIdx.x, b = blockIdx.x;
    int s0 = b * BLK, s1 = min(s0 + BLK, nE);
    if (tid == 0) {
        int nlo = nstart[b];
        sh2[0] = nlo;
        sh2[1] = nstart[b + 1] - nlo + 1;
    }
    snode[tid] = 0;
    __syncthreads();
    int nlo = sh2[0], nwin = sh2[1];
    for (int i = tid; i < nwin + 1; i += 256) woff[i] = offs[nlo + i];
    __syncthreads();
    for (int t = tid; t < nwin; t += 256) {
        int lo = max(woff[t], s0), hi = min(woff[t + 1], s1);
        for (int j = lo; j < hi; ++j) snode[j - s0] = t;
    }
    __syncthreads();

    int l = tid & 63, g = l >> 4, e = l & 15, wv = tid >> 6;
    const uint4* fb = (const uint4*)fragu;
    H8 WB0, WB1;
    WB0.u4 = fb[0 + l];
    WB1.u4 = fb[64 + l];
    f32x4 cua = ld4(pre + 64 + 8 * g), cub = ld4(pre + 64 + 8 * g + 4);
    f32x4 vBa = ld4(fold + 5120 + 8 * g), vBb = ld4(fold + 5120 + 8 * g + 4);

    for (int c = 0; c < 4; ++c) {
        int ls = wv * 64 + c * 16 + e;
        int slot = s0 + ls;
        int sc = min(slot, nE - 1);
        float a = rec[sc].a;
        int n = nlo + snode[ls];
        const float* g1p = g1 + (size_t)n * DD + 8 * g;
        f32x4 ma = lrelu4(a * cua + ld4(g1p));
        f32x4 mb = lrelu4(a * cub + ld4(g1p + 4));
        H8 B;
        B.u[0] = pkrtz(ma[0], ma[1]);
        B.u[1] = pkrtz(ma[2], ma[3]);
        B.u[2] = pkrtz(mb[0], mb[1]);
        B.u[3] = pkrtz(mb[2], mb[3]);
        f32x4 z0 = __builtin_amdgcn_mfma_f32_16x16x32_f16(WB0.h, B.h, vBa, 0, 0, 0);
        f32x4 z1 = __builtin_amdgcn_mfma_f32_16x16x32_f16(WB1.h, B.h, vBb, 0, 0, 0);
        z0 = lrelu4(z0);
        z1 = lrelu4(z1);
        *(f32x4*)&zs[ls * 36 + 8 * g] = z0;
        *(f32x4*)&zs[ls * 36 + 8 * g + 4] = z1;
    }
    __syncthreads();
    for (int t = tid; t < nwin * DD; t += 256) {
        int ln = t >> 5, f = t & 31;
        int lo = max(woff[ln], s0), hi = min(woff[ln + 1], s1);
        if (lo >= hi) continue;
        float sum = 0.f;
        for (int j = lo; j < hi; ++j) sum += zs[(j - s0) * 36 + f];
        int n = nlo + ln;
        bool interior = (woff[ln] >= s0) && (woff[ln + 1] <= s1);
        if (interior) Z1[(size_t)n * DD + f] = sum;
        else atomicAdd(&Z1[(size_t)n * DD + f], sum);
    }
}

// ---- head via MFMA; scatters exp(val) to out[e]; fused per-node denom ----
__global__ __launch_bounds__(256) void k_head3m(
    const EdgeRec* __restrict__ rec, const int* __restrict__ offs, const int* __restrict__ nstart,
    const float* __restrict__ pre, const float* __restrict__ fold,
    const unsigned* __restrict__ fragu, const float* __restrict__ hb2,
    const float* __restrict__ hw3, const float* __restrict__ hb3, const float* __restrict__ g1,
    const float* __restrict__ g2, float* __restrict__ out, float* __restrict__ denom, int nE) {
    __shared__ float evs[256];
    __shared__ int woff[260];
    __shared__ int snode[BLK];
    __shared__ int sh2[2];
    int tid = threadIdx.x, b = blockIdx.x;
    int s0 = b * BLK, s1 = min(s0 + BLK, nE);
    if (tid == 0) {
        int nlo = nstart[b];
        sh2[0] = nlo;
        sh2[1] = nstart[b + 1] - nlo + 1;
    }
    evs[tid] = 0.f;
    snode[tid] = 0;
    __syncthreads();
    int nlo = sh2[0], nwin = sh2[1];
    for (int i = tid; i < nwin + 1; i += 256) woff[i] = offs[nlo + i];
    __syncthreads();
    for (int t = tid; t < nwin; t += 256) {
        int lo = max(woff[t], s0), hi = min(woff[t + 1], s1);
        for (int j = lo; j < hi; ++j) snode[j - s0] = t;
    }
    __syncthreads();

    int l = tid & 63, g = l >> 4, e = l & 15, wv = tid >> 6;
    const uint4* fb = (const uint4*)fragu;
    H8 WA0, WA1, WE0, WE1, H0, H1;
    WA0.u4 = fb[128 + l];
    WA1.u4 = fb[192 + l];
    WE0.u4 = fb[256 + l];
    WE1.u4 = fb[320 + l];
    H0.u4 = fb[384 + l];
    H1.u4 = fb[448 + l];
    f32x4 cua = ld4(pre + 64 + 8 * g), cub = ld4(pre + 64 + 8 * g + 4);
    f32x4 cha = ld4(pre + 128 + 8 * g), chb = ld4(pre + 128 + 8 * g + 4);
    f32x4 dha = ld4(fold + 5248 + 8 * g), dhb = ld4(fold + 5248 + 8 * g + 4);
    f32x4 hb2a = ld4(hb2 + 4 * g), hb2b = ld4(hb2 + 16 + 4 * g);
    f32x4 h3a = ld4(hw3 + 4 * g), h3b = ld4(hw3 + 16 + 4 * g);
    float hb3s = hb3[0];

    for (int c = 0; c < 4; ++c) {
        int ls = wv * 64 + c * 16 + e;
        int slot = s0 + ls;
        int sc = min(slot, nE - 1);
        EdgeRec r = rec[sc];
        float a = r.a;
        int n = nlo + snode[ls];
        const float* g1p = g1 + (size_t)n * DD + 8 * g;
        f32x4 ma = lrelu4(a * cua + ld4(g1p));
        f32x4 mb = lrelu4(a * cub + ld4(g1p + 4));
        H8 B;
        B.u[0] = pkrtz(ma[0], ma[1]);
        B.u[1] = pkrtz(ma[2], ma[3]);
        B.u[2] = pkrtz(mb[0], mb[1]);
        B.u[3] = pkrtz(mb[2], mb[3]);
        const float* g2p = g2 + (size_t)n * DD + 8 * g;
        f32x4 z0 = ld4(g2p), z1 = ld4(g2p + 4);  // C_in = g2 (incl. bias)
        z0 = __builtin_amdgcn_mfma_f32_16x16x32_f16(WA0.h, B.h, z0, 0, 0, 0);
        z1 = __builtin_amdgcn_mfma_f32_16x16x32_f16(WA1.h, B.h, z1, 0, 0, 0);
        z0 = lrelu4(z0);
        z1 = lrelu4(z1);
        B.u[0] = pkrtz(z0[0], z0[1]);
        B.u[1] = pkrtz(z0[2], z0[3]);
        B.u[2] = pkrtz(z1[0], z1[1]);
        B.u[3] = pkrtz(z1[2], z1[3]);
        f32x4 v0 = a * cha + dha, v1 = a * chb + dhb;
        v0 = __builtin_amdgcn_mfma_f32_16x16x32_f16(WE0.h, B.h, v0, 0, 0, 0);
        v1 = __builtin_amdgcn_mfma_f32_16x16x32_f16(WE1.h, B.h, v1, 0, 0, 0);
        v0 = lrelu4(v0);
        v1 = lrelu4(v1);
        B.u[0] = pkrtz(v0[0], v0[1]);
        B.u[1] = pkrtz(v0[2], v0[3]);
        B.u[2] = pkrtz(v1[0], v1[1]);
        B.u[3] = pkrtz(v1[2], v1[3]);
        f32x4 w0 = hb2a, w1 = hb2b;
        w0 = __builtin_amdgcn_mfma_f32_16x16x32_f16(H0.h, B.h, w0, 0, 0, 0);
        w1 = __builtin_amdgcn_mfma_f32_16x16x32_f16(H1.h, B.h, w1, 0, 0, 0);
        w0 = lrelu4(w0);
        w1 = lrelu4(w1);
        f32x4 t = w0 * h3a + w1 * h3b;
        float val = t[0] + t[1] + t[2] + t[3];
        val += __shfl_xor(val, 16, 64);
        val += __shfl_xor(val, 32, 64);
        float exv = __expf(val + hb3s);  // max-shift dropped: logits O(1)
        if (g == 0 && slot < s1) {
            out[r.e] = exv;  // scatter numerator; k_div normalizes in place
            evs[ls] = exv;
        }
    }
    __syncthreads();
    for (int t = tid; t < nwin; t += 256) {
        int lo = max(woff[t], s0), hi = min(woff[t + 1], s1);
        if (lo >= hi) continue;
        float sum = 0.f;
        for (int j = lo; j < hi; ++j) sum += evs[j - s0];
        int n = nlo + t;
        bool interior = (woff[t] >= s0) && (woff[t + 1] <= s1);
        if (interior) denom[n] = sum;
        else atomicAdd(&denom[n], sum);
    }
}

// ---- div: out[e] /= denom[ei[e]] (coalesced; denom 200KB, L2-resident) ----
__global__ __launch_bounds__(256) void k_div(const int* __restrict__ ei,
                                             const float* __restrict__ denom,
                                             float* __restrict__ out, int nE) {
    int e = blockIdx.x * 256 + threadIdx.x;
    if (e >= nE) return;
    out[e] = out[e] / denom[ei[e]];
}

extern "C" void kernel_launch(void* const* d_in, const int* in_sizes, int n_in, void* d_out,
                              int out_size, void* d_ws, size_t ws_size, hipStream_t stream) {
    const float* ea = (const float*)d_in[0];
    const int* ei = (const int*)d_in[1];
    const float* w_in = (const float*)d_in[2];
    const float* b_in = (const float*)d_in[3];
    const float* tw1 = (const float*)d_in[4];
    const float* tb1 = (const float*)d_in[5];
    const float* tw2 = (const float*)d_in[6];
    const float* tb2 = (const float*)d_in[7];
    const float* uw1 = (const float*)d_in[8];
    const float* ub1 = (const float*)d_in[9];
    const float* uw2 = (const float*)d_in[10];
    const float* ub2 = (const float*)d_in[11];
    const float* hw1 = (const float*)d_in[12];
    const float* hb1 = (const float*)d_in[13];
    const float* hw2 = (const float*)d_in[14];
    const float* hb2 = (const float*)d_in[15];
    const float* hw3 = (const float*)d_in[16];
    const float* hb3 = (const float*)d_in[17];

    const int nE = in_sizes[0];
    const int gridB = (nE + BLK - 1) / BLK;

    // chunk log: smallest L with ceil(nE / 2^L) <= 8 chunks
    int chl = 0;
    while ((((size_t)nE + ((size_t)1 << chl) - 1) >> chl) > 8) ++chl;

    char* w = (char*)d_ws;
    size_t pos = 0;
    auto alloc = [&](size_t bytes) -> void* {
        void* p = w + pos;
        pos = (pos + bytes + 255) & ~(size_t)255;
        return p;
    };
    int* cnt = (int*)alloc((size_t)NN * 4);  // node counts -> cursors
    int* offs = (int*)alloc((size_t)(NN + 1) * 4);
    int* nstart = (int*)alloc((size_t)(gridB + 1) * 4);
    EdgeRec* rec = (EdgeRec*)alloc((size_t)nE * sizeof(EdgeRec));
    int* posArr = (int*)alloc((size_t)nE * 4);
    float* M0 = (float*)alloc((size_t)NN * DD * 4);  // M0|Z1|denom contiguous -> one memset
    float* Z1 = (float*)alloc((size_t)NN * DD * 4);
    float* denom = (float*)alloc((size_t)NN * 4);
    float* g1 = (float*)alloc((size_t)NN * DD * 4);
    float* g2 = (float*)alloc((size_t)NN * DD * 4);
    float* pre = (float*)alloc(6 * 32 * 4);
    float* fold = (float*)alloc((5 * 1024 + 5 * 32) * 4);
    unsigned* fragu = (unsigned*)alloc(2048 * 4);

    hipMemsetAsync(cnt, 0, (size_t)NN * 4, stream);
    hipMemsetAsync(M0, 0, (size_t)((char*)g1 - (char*)M0), stream);

    int gridE = (nE + 255) / 256;
    int gridNF = (NN * DD + 255) / 256;

    k_prep<<<1, 192, 0, stream>>>(w_in, b_in, tw1, tb1, uw1, ub1, hw1, hb1, pre);
    k_prep2<<<1, 256, 0, stream>>>(tw1, tb1, tw2, tb2, uw1, ub1, uw2, ub2, hw1, hw2, pre, fold,
                                   fragu);
    k_hist<<<gridE, 256, 0, stream>>>(ei, cnt, nE);
    k_scan<<<1, 1024, 0, stream>>>(cnt, offs, NN);
    k_fillA<<<gridE, 256, 0, stream>>>(ei, cnt, posArr, nE);
    k_fillB<<<8 * NSLICE, 256, 0, stream>>>(ea, posArr, rec, nE, chl);
    k_bstart<<<(gridB + 256) / 256, 256, 0, stream>>>(offs, nstart, gridB, nE);

    // layer 0
    k_accum0f<<<gridB, 256, 0, stream>>>(rec, offs, nstart, pre, M0, nE);
    k_gnode<<<gridNF, 256, 0, stream>>>(M0, fold + 2048, fold + 5152, pre + 96, offs, g1);

    // layer 1
    k_z1m<<<gridB, 256, 0, stream>>>(rec, offs, nstart, pre, fold, fragu, g1, Z1, nE);
    k_gnode<<<gridNF, 256, 0, stream>>>(Z1, fold + 3072, fold + 5184, fold + 5216, offs, g2);

    // head + denom, then coalesced divide
    k_head3m<<<gridB, 256, 0, stream>>>(rec, offs, nstart, pre, fold, fragu, hb2, hw3, hb3, g1, g2,
                                        (float*)d_out, denom, nE);
    k_div<<<gridE, 256, 0, stream>>>(ei, denom, (float*)d_out, nE);
}